// Round 12
// baseline (147.663 us; speedup 1.0000x reference)
//
#include <hip/hip_runtime.h>

// Problem constants
#define N_ROWS 131072    // 32*4096
#define D 64
#define K_CODES 1024

typedef _Float16 f16x8 __attribute__((ext_vector_type(8)));
typedef float    f32x4 __attribute__((ext_vector_type(4)));

#define MFMA16(a, b, c) __builtin_amdgcn_mfma_f32_16x16x32_f16((a), (b), (c), 0, 0, 0)

// ---------------------------------------------------------------------------
// ws layout: csqr[1024] f32 (4 KB) | CBf: 16384 f16x8 units (256 KB)
// 16x16x32 fragment order. CBf unit index = tile*256 + f*64 + lane,
// f in {0:hi k0-31, 1:hi k32-63, 2:lo k0-31, 3:lo k32-63}; unit holds the
// 8 halves lane needs for that MFMA B fragment:
// B[k=(lane>>4)*8+j][n=lane&15], code = tile*16 + n.
// CBf stores the hi/lo split of (-2*c); dist = |c|^2 + x.(-2c).
// (Correctness-verified rounds 2-5, 7-10.)
// ---------------------------------------------------------------------------
__global__ __launch_bounds__(256)
void prep_kernel(const float* __restrict__ CB, _Float16* __restrict__ CBf,
                 float* __restrict__ csqr, float* __restrict__ loss) {
    const int b = blockIdx.x, t = threadIdx.x;
    if (b < 64) {
        const int unit = b * 256 + t;
        const int tile = unit >> 8;
        const int f    = (unit >> 6) & 3;
        const int lane = unit & 63;
        const int quad = lane >> 4, lrow = lane & 15;
        const int code = tile * 16 + lrow;
        const int k0   = (f & 1) * 32 + quad * 8;
        const float* src = CB + (size_t)code * D + k0;
        float4 v0 = *(const float4*)(src);
        float4 v1 = *(const float4*)(src + 4);
        float xs[8] = {v0.x, v0.y, v0.z, v0.w, v1.x, v1.y, v1.z, v1.w};
        f16x8 o;
#pragma unroll
        for (int j = 0; j < 8; ++j) {
            float sv = -2.0f * xs[j];
            _Float16 h = (_Float16)sv;
            o[j] = (f < 2) ? h : (_Float16)(sv - (float)h);
        }
        *(f16x8*)(CBf + (size_t)unit * 8) = o;
    } else {
        if (t == 0) *loss = 0.0f;
        for (int k = t; k < K_CODES; k += 256) {
            const float4* p = (const float4*)(CB + (size_t)k * D);
            float s = 0.0f;
#pragma unroll
            for (int i = 0; i < 16; ++i) {
                float4 v = p[i];
                s += v.x * v.x + v.y * v.y + v.z * v.z + v.w * v.w;
            }
            csqr[k] = s;
        }
    }
}

// ---------------------------------------------------------------------------
// Direct global->LDS 16B copy (lane-linear dest: wave-uniform base + lane*16).
// ---------------------------------------------------------------------------
__device__ __forceinline__ void gload_lds16(const void* g, void* l) {
    __builtin_amdgcn_global_load_lds(
        (const __attribute__((address_space(1))) void*)g,
        (__attribute__((address_space(3))) void*)l,
        16, 0, 0);
}

// ---------------------------------------------------------------------------
// K1 (128-reg waves + 2-deep LDS pipeline) — RESUBMIT of round 11 (bench
// infra failed; kernel unmeasured). Theory: R10 post-mortem — per-CU pipe
// budgets (MFMA 59.6k cyc = 38%, LDS 49k = 32%, VALU 8% of 156k) SUM
// instead of overlapping: every R3-R10 kernel ran at the 64-VGPR allocator
// cap (= 256/min_waves), leaving zero regs for read-ahead -> depth-1
// serial waves (R5's "pipeline" collapsed to 64 regs — never actually
// tested). CHANGE: __launch_bounds__(512,2) -> 128-reg budget at the SAME
// occupancy (128-reg = 4 waves/SIMD; LDS 69 KB = 2 blocks/CU; grid 512
// exact), and the 16-tile pass loop becomes a fully-unrolled 2-deep
// software pipeline: B1's 4 ds_read_b128 issue BEFORE tile-B0's 12-MFMA
// cluster; counted lgkmcnt(4) + sched_barrier(0) (rule #18) pin the
// schedule; per-pass cs[16] prefetched ahead of the B stream (in-order DS
// retirement keeps lgkmcnt(4) exact: cs ops are oldest). Reg tally: A 32 +
// B0/B1 32 + cs 16 + best 16 + acc 8 + misc ~= 115 < 128.
// Macro-structure = R10 verbatim: 4 passes x 64 KB single-buffer stage,
// free-run inside pass, 8 barriers total; MT=2; split numerics (hh,hh,lh,
// lh,hl,hl; ll dropped); acc-init=csqr; first-min tie-break (codes ascend
// with (p,tile): strict <; 16-lane column reduce index-lexicographic);
// 256-row zq epilogue. All correctness-verified in prior rounds.
// ---------------------------------------------------------------------------
__global__ __launch_bounds__(512, 2)
void argmin_kernel(const float* __restrict__ X,
                   const _Float16* __restrict__ CBf,
                   const float* __restrict__ csqr,
                   const float* __restrict__ CB,
                   float* __restrict__ out) {
    __shared__ _Float16 Bbuf[16][2048];   // 64 KB: 16 tiles x 4 KB (one pass)
    __shared__ float LsC[K_CODES];        // csqr copy, 4 KB
    __shared__ int   ivfin[256];
    __shared__ float lsum[8];

    const int t    = threadIdx.x;         // 0..511
    const int wave = t >> 6;              // 0..7
    const int lane = t & 63;
    const int quad = lane >> 4;
    const int lrow = lane & 15;
    const int R0   = blockIdx.x * 256;
    const int Rw   = R0 + wave * 32;      // this wave's 32 rows

// Stage pass p (16 tiles = 4096 units of 16B): 512 threads x 8 gload_lds.
#define STAGE(p_)                                                             \
    do {                                                                      \
        _Pragma("unroll")                                                     \
        for (int i_ = 0; i_ < 8; ++i_) {                                      \
            const int u_ = i_ * 512 + t;                                      \
            const f16x8* gp_ =                                                \
                (const f16x8*)CBf + (size_t)((p_) * 4096 + u_);               \
            gload_lds16((const void*)gp_,                                     \
                        (void*)((char*)&Bbuf[0][0] + (size_t)u_ * 16));       \
        }                                                                     \
    } while (0)

// Issue tile i_'s 4 B-fragment ds_read_b128 into named reg buffer Bv.
#define READB(Bv, i_)                                                         \
    do {                                                                      \
        const f16x8* Bt_ = (const f16x8*)&Bbuf[i_][0] + lane;                 \
        Bv[0] = Bt_[0];                                                       \
        Bv[1] = Bt_[64];                                                      \
        Bv[2] = Bt_[128];                                                     \
        Bv[3] = Bt_[192];                                                     \
    } while (0)

#define SBAR() __builtin_amdgcn_sched_barrier(0)
#define WAITK(n_) asm volatile("s_waitcnt lgkmcnt(" #n_ ")" ::: "memory")

// 12-MFMA cluster + argmin for tile i_ of pass p_ with acc-init cs_.
// Codes ascend with (p,tile): strict < keeps np.argmin first-min.
#define TILECOMP(Bv, p_, i_, cs_)                                             \
    do {                                                                      \
        const int c_ = ((p_) * 16 + (i_)) * 16 + lrow;                        \
        _Pragma("unroll")                                                     \
        for (int mt = 0; mt < 2; ++mt) {                                      \
            f32x4 acc = {cs_, cs_, cs_, cs_};                                 \
            acc = MFMA16(Ah[mt][0], Bv[0], acc);                              \
            acc = MFMA16(Ah[mt][1], Bv[1], acc);                              \
            acc = MFMA16(Al[mt][0], Bv[0], acc);                              \
            acc = MFMA16(Al[mt][1], Bv[1], acc);                              \
            acc = MFMA16(Ah[mt][0], Bv[2], acc);                              \
            acc = MFMA16(Ah[mt][1], Bv[3], acc);                              \
            _Pragma("unroll")                                                 \
            for (int r = 0; r < 4; ++r) {                                     \
                bool lt = acc[r] < bestd[mt][r];                              \
                bestd[mt][r] = lt ? acc[r] : bestd[mt][r];                    \
                besti[mt][r] = lt ? c_ : besti[mt][r];                        \
            }                                                                 \
        }                                                                     \
    } while (0)

    STAGE(0);                          // pass-0 B in flight ASAP

    // csqr -> LDS (covered by the prologue __syncthreads).
    if (t < 256) ((float4*)LsC)[t] = ((const float4*)csqr)[t];

    // ---- A fragments (MT=2): split(x) hi/lo. Lane holds
    // A[m=lrow][k=quad*8+j] for rows Rw+mt*16+lrow.
    f16x8 Ah[2][2], Al[2][2];
    float xsq = 0.0f;
#pragma unroll
    for (int mt = 0; mt < 2; ++mt) {
        const float* xr = X + (size_t)(Rw + mt * 16 + lrow) * D;
#pragma unroll
        for (int ks = 0; ks < 2; ++ks) {
            const int k0 = ks * 32 + quad * 8;
            float4 v0 = *(const float4*)(xr + k0);
            float4 v1 = *(const float4*)(xr + k0 + 4);
            float xs[8] = {v0.x, v0.y, v0.z, v0.w, v1.x, v1.y, v1.z, v1.w};
            f16x8 h, l;
#pragma unroll
            for (int j = 0; j < 8; ++j) {
                xsq += xs[j] * xs[j];
                _Float16 hh = (_Float16)xs[j];
                h[j] = hh;
                l[j] = (_Float16)(xs[j] - (float)hh);
            }
            Ah[mt][ks] = h;
            Al[mt][ks] = l;
        }
    }

    float bestd[2][4];
    int   besti[2][4];
#pragma unroll
    for (int mt = 0; mt < 2; ++mt)
#pragma unroll
        for (int r = 0; r < 4; ++r) { bestd[mt][r] = 3.0e38f; besti[mt][r] = 0; }

    __syncthreads();   // pass-0 B + LsC + A ready (full drain, prologue)

    // ---- 4 passes x 16 tiles, 2-deep pinned pipeline inside each pass.
    for (int p = 0; p < 4; ++p) {
        if (p) {
            __syncthreads();           // all waves done reading pass p-1
            STAGE(p);
            asm volatile("s_waitcnt vmcnt(0)" ::: "memory");
            __syncthreads();           // pass-p B visible to all waves
        }
        // cs prefetch: 16 DS reads, oldest in the queue -> every later
        // lgkmcnt(4) retires them plus the current B buffer exactly.
        float cs[16];
#pragma unroll
        for (int i = 0; i < 16; ++i) cs[i] = LsC[p * 256 + i * 16 + lrow];
        SBAR();
        f16x8 B0[4], B1[4];
        READB(B0, 0);
        SBAR();
#pragma unroll
        for (int s = 0; s < 8; ++s) {
            READB(B1, 2 * s + 1);      // next tile's reads BEFORE compute
            SBAR();
            WAITK(4);                  // B0 ready; B1's 4 still in flight
            SBAR();
            TILECOMP(B0, p, 2 * s, cs[2 * s]);
            SBAR();
            if (s < 7) {
                READB(B0, 2 * s + 2);
                SBAR();
                WAITK(4);              // B1 ready; B0's 4 in flight
            } else {
                WAITK(0);              // drain for the last tile
            }
            SBAR();
            TILECOMP(B1, p, 2 * s + 1, cs[2 * s + 1]);
            SBAR();
        }
    }

    // ---- Finalize: 16-lane column reduce (lexicographic on exact ties);
    // lrow==0 lanes hold rows Rw + mt*16 + quad*4 + r (C layout:
    // row = quad*4 + r, col = lrow — verified rounds 0-10).
    float dvsum = 0.0f;
#pragma unroll
    for (int mt = 0; mt < 2; ++mt) {
#pragma unroll
        for (int r = 0; r < 4; ++r) {
            float dv = bestd[mt][r];
            int   iv = besti[mt][r];
#pragma unroll
            for (int m = 1; m < 16; m <<= 1) {
                float od = __shfl_xor(dv, m, 64);
                int   oi = __shfl_xor(iv, m, 64);
                if (od < dv || (od == dv && oi < iv)) { dv = od; iv = oi; }
            }
            if (lrow == 0) {
                const int rl = wave * 32 + mt * 16 + quad * 4 + r;  // 0..255
                ivfin[rl] = iv;
                out[1 + (size_t)N_ROWS * D + R0 + rl] = (float)iv;  // idxf
                dvsum += dv;
            }
        }
    }

    // ---- Loss partial: xsq (all lanes) + dvsum (lrow==0 lanes) reduce.
    {
        float s = xsq + dvsum;
#pragma unroll
        for (int m = 1; m < 64; m <<= 1) s += __shfl_xor(s, m, 64);
        if (lane == 0) lsum[wave] = s;
    }
    __syncthreads();                             // ivfin + lsum ready

    const float scale = 1.25f / (float)((size_t)N_ROWS * D);
    if (t == 0) {
        float L = 0.0f;
#pragma unroll
        for (int w = 0; w < 8; ++w) L += lsum[w];
        atomicAdd(out, L * scale);
    }

    // ---- Block-cooperative zq span write: dwords [R0*64, R0*64+16384) at
    // out+1. Global dword offset 1+R0*64+j is 16B-aligned iff j%4==3.
    float* p = out + 1 + (size_t)R0 * D;
#pragma unroll
    for (int i = 0; i < 8; ++i) {
        int q = i * 512 + t;        // 0..4095
        int j = 4 * q + 3;          // 3,7,...,16383
        if (q < 4095) {
            float v[4];
#pragma unroll
            for (int e = 0; e < 4; ++e) {
                int jj = j + e;     // may straddle a row boundary
                v[e] = CB[(size_t)ivfin[jj >> 6] * D + (jj & 63)];
            }
            *(float4*)(p + j) = make_float4(v[0], v[1], v[2], v[3]);
        } else if (q == 4095) {
            p[16383] = CB[(size_t)ivfin[255] * D + 63];
        }
    }
    if (t == 0) {   // head dwords j=0..2 (row 0, cols 0..2)
        const float* c0 = CB + (size_t)ivfin[0] * D;
        p[0] = c0[0];
        p[1] = c0[1];
        p[2] = c0[2];
    }
}

// ---------------------------------------------------------------------------
extern "C" void kernel_launch(void* const* d_in, const int* in_sizes, int n_in,
                              void* d_out, int out_size, void* d_ws,
                              size_t ws_size, hipStream_t stream) {
    const float* X  = (const float*)d_in[0];   // inputs  [131072,64]
    const float* CB = (const float*)d_in[1];   // codebook [1024,64]

    float*    csqr = (float*)d_ws;                      // 4 KB
    _Float16* CBf  = (_Float16*)((char*)d_ws + 4096);   // 256 KB

    hipLaunchKernelGGL(prep_kernel, dim3(65), dim3(256), 0, stream,
                       CB, CBf, csqr, (float*)d_out);
    hipLaunchKernelGGL(argmin_kernel, dim3(N_ROWS / 256), dim3(512), 0, stream,
                       X, CBf, csqr, CB, (float*)d_out);
}